// Round 1
// baseline (35.684 us; speedup 1.0000x reference)
//
#include <hip/hip_runtime.h>

// Decoder: out[b,n,:] = relu([v_bn, emb[n]] @ W1 + b1) @ W2 + b2
//   where v_bn = abs_actions[b, asgn[b,n]]
// Split:  base[n,h] = emb[n]@W1[1:,h] + b1[h]     (b-independent, phase 1)
//         out[b,n]  = relu(base[n,:] + v*W1[0,:]) @ W2 + b2   (phase 2)

constexpr int B_ = 32, A_ = 16, N_ = 10000, E_ = 256, H_ = 256;
constexpr int TN   = 40;          // n-rows per block; 250 * 40 == 10000 exactly (no tail)
constexpr int NBLK = N_ / TN;     // 250 blocks -> ~1 per CU, perfectly balanced

__global__ __launch_bounds__(256, 1) void decoder_fused(
    const float* __restrict__ abs_actions,  // (32,16)
    const int*   __restrict__ asgn,         // (32,10000)
    const float* __restrict__ emb,          // (10000,256)
    const float* __restrict__ W1,           // (257,256)
    const float* __restrict__ b1,           // (256)
    const float* __restrict__ W2,           // (256,2)
    const float* __restrict__ b2,           // (2)
    float* __restrict__ out)                // (32,10000,2)
{
    // union: emb tile [40][256] during phase 1, then base tile [40][260] (padded pitch)
    __shared__ float u[TN * 260];           // 41600 B
    __shared__ float vals[B_ * 41];         // v[b][n] for tile, padded pitch 41
    __shared__ float w1r[H_];               // W1 row 0
    __shared__ float w2s[2 * H_];           // W2 interleaved [h][o]

    const int t  = threadIdx.x;
    const int n0 = blockIdx.x * TN;

    // ---- stage emb tile (coalesced float4): 40*256 fp32 = 2560 float4, 10/thread
    {
        const float4* src = reinterpret_cast<const float4*>(emb + (size_t)n0 * E_);
        float4* dst = reinterpret_cast<float4*>(u);
        #pragma unroll
        for (int q = 0; q < 10; ++q) dst[t + 256 * q] = src[t + 256 * q];
    }
    // ---- stage W1 row0 and W2
    w1r[t]       = W1[t];          // W1[0][t]
    w2s[t]       = W2[t];
    w2s[256 + t] = W2[256 + t];
    // ---- stage vals[b][n] = abs_actions[b, asgn[b, n0+n]]
    #pragma unroll
    for (int q = 0; q < 5; ++q) {
        int p = t + 256 * q;                 // 0..1279 = 32*40
        int b = p / 40, n = p - b * 40;
        int a = asgn[b * N_ + n0 + n];
        vals[b * 41 + n] = abs_actions[b * A_ + a];
    }
    __syncthreads();

    // ================= phase 1: base tile GEMM (fp32 VALU) =================
    // wave w owns n-rows [10w, 10w+10); each lane owns 4 h-cols (h0 = 4*lane)
    const int hq = t & 63;
    const int h0 = hq * 4;
    const int ng = t >> 6;                   // wave id 0..3
    const int nb = ng * 10;

    float acc[10][4];
    {
        const float4 bv = *reinterpret_cast<const float4*>(b1 + h0);
        #pragma unroll
        for (int i = 0; i < 10; ++i) {
            acc[i][0] = bv.x; acc[i][1] = bv.y; acc[i][2] = bv.z; acc[i][3] = bv.w;
        }
    }

    const float* pw = W1 + E_ + h0;          // W1 rows 1.., columns h0..h0+3
    // double-buffered W1 row registers (rows k..k+3)
    float4 wa = *reinterpret_cast<const float4*>(pw + 0 * 256);
    float4 wb = *reinterpret_cast<const float4*>(pw + 1 * 256);
    float4 wc = *reinterpret_cast<const float4*>(pw + 2 * 256);
    float4 wd = *reinterpret_cast<const float4*>(pw + 3 * 256);

    for (int k = 0; k < 256; k += 4) {
        const int kn = (k + 4) & 255;        // wraps to row 1 on last iter (valid, unused)
        float4 na_ = *reinterpret_cast<const float4*>(pw + (kn + 0) * 256);
        float4 nb_ = *reinterpret_cast<const float4*>(pw + (kn + 1) * 256);
        float4 nc_ = *reinterpret_cast<const float4*>(pw + (kn + 2) * 256);
        float4 nd_ = *reinterpret_cast<const float4*>(pw + (kn + 3) * 256);
        #pragma unroll
        for (int i = 0; i < 10; ++i) {
            const float4 e = *reinterpret_cast<const float4*>(&u[(nb + i) * 256 + k]);
            acc[i][0] = fmaf(e.x, wa.x, acc[i][0]);
            acc[i][0] = fmaf(e.y, wb.x, acc[i][0]);
            acc[i][0] = fmaf(e.z, wc.x, acc[i][0]);
            acc[i][0] = fmaf(e.w, wd.x, acc[i][0]);
            acc[i][1] = fmaf(e.x, wa.y, acc[i][1]);
            acc[i][1] = fmaf(e.y, wb.y, acc[i][1]);
            acc[i][1] = fmaf(e.z, wc.y, acc[i][1]);
            acc[i][1] = fmaf(e.w, wd.y, acc[i][1]);
            acc[i][2] = fmaf(e.x, wa.z, acc[i][2]);
            acc[i][2] = fmaf(e.y, wb.z, acc[i][2]);
            acc[i][2] = fmaf(e.z, wc.z, acc[i][2]);
            acc[i][2] = fmaf(e.w, wd.z, acc[i][2]);
            acc[i][3] = fmaf(e.x, wa.w, acc[i][3]);
            acc[i][3] = fmaf(e.y, wb.w, acc[i][3]);
            acc[i][3] = fmaf(e.z, wc.w, acc[i][3]);
            acc[i][3] = fmaf(e.w, wd.w, acc[i][3]);
        }
        wa = na_; wb = nb_; wc = nc_; wd = nd_;
    }

    __syncthreads();   // all emb reads complete before overwriting union buffer
    #pragma unroll
    for (int i = 0; i < 10; ++i) {
        float4 v; v.x = acc[i][0]; v.y = acc[i][1]; v.z = acc[i][2]; v.w = acc[i][3];
        *reinterpret_cast<float4*>(&u[(nb + i) * 260 + h0]) = v;  // pitch 260: 16B-aligned
    }
    __syncthreads();

    // ================= phase 2: out[b,n,:] = relu(base + v*w1r) @ W2 + b2 =================
    // 1280 (b,n) pairs, 5 per thread; p = t + 256q -> b = p/40 (n fast => coalesced stores)
    const float2 b2v = *reinterpret_cast<const float2*>(b2);
    float oacc[5][2];
    int   pn[5], pb[5];
    float pv[5];
    #pragma unroll
    for (int q = 0; q < 5; ++q) {
        int p = t + 256 * q;
        int b = p / 40, n = p - b * 40;
        pb[q] = b; pn[q] = n;
        pv[q] = vals[b * 41 + n];
        oacc[q][0] = 0.f; oacc[q][1] = 0.f;
    }

    #pragma unroll 2
    for (int h = 0; h < 256; h += 4) {
        const float4 wv = *reinterpret_cast<const float4*>(&w1r[h]);
        const float4 p0 = *reinterpret_cast<const float4*>(&w2s[2 * h]);
        const float4 p1 = *reinterpret_cast<const float4*>(&w2s[2 * h + 4]);
        #pragma unroll
        for (int q = 0; q < 5; ++q) {
            const float4 c = *reinterpret_cast<const float4*>(&u[pn[q] * 260 + h]);
            const float v = pv[q];
            float t0 = fmaxf(fmaf(v, wv.x, c.x), 0.f);
            float t1 = fmaxf(fmaf(v, wv.y, c.y), 0.f);
            float t2 = fmaxf(fmaf(v, wv.z, c.z), 0.f);
            float t3 = fmaxf(fmaf(v, wv.w, c.w), 0.f);
            oacc[q][0] = fmaf(t0, p0.x, oacc[q][0]);
            oacc[q][1] = fmaf(t0, p0.y, oacc[q][1]);
            oacc[q][0] = fmaf(t1, p0.z, oacc[q][0]);
            oacc[q][1] = fmaf(t1, p0.w, oacc[q][1]);
            oacc[q][0] = fmaf(t2, p1.x, oacc[q][0]);
            oacc[q][1] = fmaf(t2, p1.y, oacc[q][1]);
            oacc[q][0] = fmaf(t3, p1.z, oacc[q][0]);
            oacc[q][1] = fmaf(t3, p1.w, oacc[q][1]);
        }
    }

    #pragma unroll
    for (int q = 0; q < 5; ++q) {
        float2 o; o.x = oacc[q][0] + b2v.x; o.y = oacc[q][1] + b2v.y;
        *reinterpret_cast<float2*>(out + ((size_t)pb[q] * N_ + n0 + pn[q]) * 2) = o;
    }
}

extern "C" void kernel_launch(void* const* d_in, const int* in_sizes, int n_in,
                              void* d_out, int out_size, void* d_ws, size_t ws_size,
                              hipStream_t stream) {
    const float* abs_actions = (const float*)d_in[0];
    const int*   asgn        = (const int*)d_in[1];
    const float* emb         = (const float*)d_in[2];
    const float* W1          = (const float*)d_in[3];
    const float* b1          = (const float*)d_in[4];
    const float* W2          = (const float*)d_in[5];
    const float* b2          = (const float*)d_in[6];
    float*       out         = (float*)d_out;

    decoder_fused<<<NBLK, 256, 0, stream>>>(abs_actions, asgn, emb, W1, b1, W2, b2, out);
}

// Round 4
// 30.611 us; speedup vs baseline: 1.1657x; 1.1657x over previous
//
#include <hip/hip_runtime.h>

// out[b,n,:] = relu([v_bn, emb[n]] @ W1 + b1) @ W2 + b2,  v_bn = abs_actions[b, asgn[b,n]]
// Split: base[n,h] = emb[n]@W1[1:,h] + b1[h]  (b-independent -> bf16 MFMA)
//        out[b,n]  = relu(base[n,:] + v*W1[0,:]) @ W2 + b2  (fp32 VALU, r1-verified structure)

constexpr int B_ = 32, A_ = 16, N_ = 10000, E_ = 256, H_ = 256;
constexpr int TN = 16, NBLK = N_ / TN;   // 625 blocks, 10000 exactly

typedef __attribute__((ext_vector_type(8))) short bf16x8;
typedef __attribute__((ext_vector_type(4))) float f32x4;

// static device global: rewritten every call (deterministic, capture-safe)
__device__ __align__(16) ushort g_w1t[H_ * E_];   // [h][k] bf16 of W1[1+k][h]

static __device__ __forceinline__ ushort f2bf(float x) {
    union { float f; unsigned u; } c; c.f = x;
    unsigned r = c.u + 0x7fff + ((c.u >> 16) & 1);   // RNE
    return (ushort)(r >> 16);
}

__global__ __launch_bounds__(256, 1) void prep_w1t_k(const float* __restrict__ W1) {
    __shared__ float tile[64][65];
    const int bk = blockIdx.x >> 2, bh = blockIdx.x & 3;
    const int tx = threadIdx.x & 63, ty = threadIdx.x >> 6;
    #pragma unroll
    for (int kk = ty; kk < 64; kk += 4)
        tile[kk][tx] = W1[(size_t)(1 + bk * 64 + kk) * H_ + bh * 64 + tx];
    __syncthreads();
    #pragma unroll
    for (int hh = ty; hh < 64; hh += 4)
        g_w1t[(size_t)(bh * 64 + hh) * E_ + bk * 64 + tx] = f2bf(tile[tx][hh]);
}

__global__ __launch_bounds__(256, 2) void decoder_main(
    const float* __restrict__ abs_actions,  // (32,16)
    const int*   __restrict__ asgn,         // (32,10000)
    const float* __restrict__ emb,          // (10000,256)
    const float* __restrict__ W1,           // (257,256)
    const float* __restrict__ b1,           // (256)
    const float* __restrict__ W2,           // (256,2)
    const float* __restrict__ b2,           // (2)
    float* __restrict__ out)                // (32,10000,2)
{
    __shared__ ushort eb[TN * 264];     // emb tile bf16, pitch 264
    __shared__ float  u[TN * 260];      // base tile f32, pitch 260
    __shared__ float  vals[B_ * 17];    // v[b][n], pitch 17
    __shared__ float  w1r[H_];          // W1 row 0
    __shared__ float  w2s[2 * H_];      // W2 flat [h*2+o]

    const int t  = threadIdx.x;
    const int n0 = blockIdx.x * TN;

    // ---- stage vals (r1-verified formula, pitch 17)
    #pragma unroll
    for (int q = 0; q < 2; ++q) {
        const int p = t + 256 * q, b = p >> 4, n = p & 15;
        vals[b * 17 + n] = abs_actions[b * A_ + asgn[(size_t)b * N_ + n0 + n]];
    }

    // ---- stage emb tile -> bf16 LDS (coalesced 64B/thread)
    {
        const int row = t >> 4, col = (t & 15) << 4;
        const float4* src = reinterpret_cast<const float4*>(emb + (size_t)(n0 + row) * E_ + col);
        const float4 q0 = src[0], q1 = src[1], q2 = src[2], q3 = src[3];
        union { ushort us[16]; bf16x8 v[2]; } pk;
        const float f[16] = {q0.x,q0.y,q0.z,q0.w, q1.x,q1.y,q1.z,q1.w,
                             q2.x,q2.y,q2.z,q2.w, q3.x,q3.y,q3.z,q3.w};
        #pragma unroll
        for (int i = 0; i < 16; ++i) pk.us[i] = f2bf(f[i]);
        bf16x8* dst = reinterpret_cast<bf16x8*>(&eb[row * 264 + col]);
        dst[0] = pk.v[0]; dst[1] = pk.v[1];
    }
    w1r[t]       = W1[t];
    w2s[t]       = W2[t];
    w2s[256 + t] = W2[256 + t];
    __syncthreads();

    // ---- phase 1: base = emb @ W1[1:] + b1 (MFMA 16x16x32 bf16; identical to r3)
    {
        const int lane = t & 63, w = t >> 6;
        const int lr = lane & 15;          // A-row (n) / B,D-col (h)
        const int lk = (lane >> 4) << 3;   // k-slice within K=32
        f32x4 acc[4];
        #pragma unroll
        for (int ct = 0; ct < 4; ++ct) {
            const float bv = b1[w * 64 + ct * 16 + lr];
            acc[ct] = (f32x4){bv, bv, bv, bv};
        }
        #pragma unroll
        for (int ks = 0; ks < 8; ++ks) {
            const bf16x8 af = *reinterpret_cast<const bf16x8*>(&eb[lr * 264 + ks * 32 + lk]);
            #pragma unroll
            for (int ct = 0; ct < 4; ++ct) {
                const bf16x8 bfv = *reinterpret_cast<const bf16x8*>(
                    &g_w1t[(size_t)(w * 64 + ct * 16 + lr) * E_ + ks * 32 + lk]);
                acc[ct] = __builtin_amdgcn_mfma_f32_16x16x32_bf16(af, bfv, acc[ct], 0, 0, 0);
            }
        }
        // D: col = lane&15, row = (lane>>4)*4 + reg   [m89-verified]
        #pragma unroll
        for (int ct = 0; ct < 4; ++ct)
            #pragma unroll
            for (int r = 0; r < 4; ++r)
                u[((lane >> 4) * 4 + r) * 260 + w * 64 + ct * 16 + lr] = acc[ct][r];
    }
    __syncthreads();

    // ---- phase 2: r1-verified structure — 512 (b,n) pairs, 2/thread, full-h loop
    {
        const float2 b2v = { b2[0], b2[1] };
        float oacc[2][2];
        int   pnn[2], pbb[2];
        float pv[2];
        #pragma unroll
        for (int q = 0; q < 2; ++q) {
            const int p = t + 256 * q, b = p >> 4, n = p & 15;
            pbb[q] = b; pnn[q] = n;
            pv[q] = vals[b * 17 + n];
            oacc[q][0] = 0.f; oacc[q][1] = 0.f;
        }

        #pragma unroll 2
        for (int h = 0; h < 256; h += 4) {
            const float4 wv = *reinterpret_cast<const float4*>(&w1r[h]);
            const float4 p0 = *reinterpret_cast<const float4*>(&w2s[2 * h]);
            const float4 p1 = *reinterpret_cast<const float4*>(&w2s[2 * h + 4]);
            #pragma unroll
            for (int q = 0; q < 2; ++q) {
                const float4 c = *reinterpret_cast<const float4*>(&u[pnn[q] * 260 + h]);
                const float v = pv[q];
                const float t0 = fmaxf(fmaf(v, wv.x, c.x), 0.f);
                const float t1 = fmaxf(fmaf(v, wv.y, c.y), 0.f);
                const float t2 = fmaxf(fmaf(v, wv.z, c.z), 0.f);
                const float t3 = fmaxf(fmaf(v, wv.w, c.w), 0.f);
                oacc[q][0] = fmaf(t0, p0.x, oacc[q][0]);
                oacc[q][1] = fmaf(t0, p0.y, oacc[q][1]);
                oacc[q][0] = fmaf(t1, p0.z, oacc[q][0]);
                oacc[q][1] = fmaf(t1, p0.w, oacc[q][1]);
                oacc[q][0] = fmaf(t2, p1.x, oacc[q][0]);
                oacc[q][1] = fmaf(t2, p1.y, oacc[q][1]);
                oacc[q][0] = fmaf(t3, p1.z, oacc[q][0]);
                oacc[q][1] = fmaf(t3, p1.w, oacc[q][1]);
            }
        }

        #pragma unroll
        for (int q = 0; q < 2; ++q) {
            float2 o; o.x = oacc[q][0] + b2v.x; o.y = oacc[q][1] + b2v.y;
            *reinterpret_cast<float2*>(out + ((size_t)pbb[q] * N_ + n0 + pnn[q]) * 2) = o;
        }
    }
}

extern "C" void kernel_launch(void* const* d_in, const int* in_sizes, int n_in,
                              void* d_out, int out_size, void* d_ws, size_t ws_size,
                              hipStream_t stream) {
    const float* abs_actions = (const float*)d_in[0];
    const int*   asgn        = (const int*)d_in[1];
    const float* emb         = (const float*)d_in[2];
    const float* W1          = (const float*)d_in[3];
    const float* b1          = (const float*)d_in[4];
    const float* W2          = (const float*)d_in[5];
    const float* b2          = (const float*)d_in[6];
    float*       out         = (float*)d_out;

    prep_w1t_k<<<16, 256, 0, stream>>>(W1);
    decoder_main<<<NBLK, 256, 0, stream>>>(abs_actions, asgn, emb, W1, b1, W2, b2, out);
}